// Round 7
// baseline (126.288 us; speedup 1.0000x reference)
//
#include <hip/hip_runtime.h>

// FDLT: out[b,m,o] = sum_i psiHat[b,m,i] * E[m][i][o]
//   E[m] = cm * X_parity(m) @ D[m]^T   (X = XFc even m, XFs odd m)
// BATCH=2048, B=128 (m), N=256 (i), O=128 (o)
//
// Kernel 1: e_kernel -> Bpack[m][t][cf][lane]·16B (MFMA fragment-packed, so
//   main-kernel B-loads are wave-uniform base + lane*16: dense 1KB bursts).
// Kernel 2: r6 pipeline, but blocks now span 4 CONSECUTIVE m (wave w owns
//   m = 4*bx + w) with b-tile 32. DRAM sees 4KB-contiguous reads per b-row
//   and 2KB-contiguous writes, vs r6's 128B shreds -> row-buffer efficiency.

typedef __attribute__((ext_vector_type(8))) short short8;
typedef __attribute__((ext_vector_type(4))) float f32x4;

#define NBATCH 2048
#define NM 128
#define NI 256   // K dim (i / j)
#define NO 128   // output o dim
// Bpack per m: 8 t-steps x 8 cf x 64 lanes x 8 bf16 = 32768 shorts (64 KB)
#define BPACK_M 32768

__device__ __forceinline__ unsigned short f2bf(float f) {
  // round-to-nearest-even fp32 -> bf16
  unsigned int u = __builtin_bit_cast(unsigned int, f);
  u += 0x7FFFu + ((u >> 16) & 1u);
  return (unsigned short)(u >> 16);
}

__device__ __forceinline__ short8 cvt8(float4 a, float4 b, float s) {
  short8 v;
  v[0] = (short)f2bf(s * a.x); v[1] = (short)f2bf(s * a.y);
  v[2] = (short)f2bf(s * a.z); v[3] = (short)f2bf(s * a.w);
  v[4] = (short)f2bf(s * b.x); v[5] = (short)f2bf(s * b.y);
  v[6] = (short)f2bf(s * b.z); v[7] = (short)f2bf(s * b.w);
  return v;
}

// ---------------- Kernel 1: E precompute -> fragment-packed Bpack ----------
__global__ __launch_bounds__(256) void e_kernel(
    const float* __restrict__ XFc, const float* __restrict__ XFs,
    const float* __restrict__ D, const float* __restrict__ cmp,
    unsigned short* __restrict__ Bpack)
{
  const int m = blockIdx.x >> 1;
  const int ihalf = blockIdx.x & 1;
  const int tid = threadIdx.x;
  const int lane = tid & 63;
  const int w = tid >> 6;
  const int lr = lane & 15;   // frag row (A) / col (B)
  const int lg = lane >> 4;   // k group
  const float cm = cmp[0];
  const float* __restrict__ Xp = (m & 1) ? XFs : XFc;
  const float* __restrict__ Dm = D + (size_t)m * (NO * NI);
  const int i0 = ihalf * 128 + w * 32;   // multiple of 32

  f32x4 acc[2][8];
#pragma unroll
  for (int a = 0; a < 2; a++)
#pragma unroll
    for (int b = 0; b < 8; b++) acc[a][b] = (f32x4)0.f;

  for (int kk = 0; kk < NI; kk += 32) {
    const int kb = kk + lg * 8;
    short8 af[2];
#pragma unroll
    for (int rf = 0; rf < 2; rf++) {
      const float* ap = Xp + (size_t)(i0 + rf * 16 + lr) * NI + kb;
      float4 x0 = *(const float4*)ap;
      float4 x1 = *(const float4*)(ap + 4);
      af[rf] = cvt8(x0, x1, cm);
    }
    short8 bf[8];
#pragma unroll
    for (int cf = 0; cf < 8; cf++) {
      const float* bp = Dm + (size_t)(cf * 16 + lr) * NI + kb;
      float4 x0 = *(const float4*)bp;
      float4 x1 = *(const float4*)(bp + 4);
      bf[cf] = cvt8(x0, x1, 1.0f);
    }
#pragma unroll
    for (int rf = 0; rf < 2; rf++)
#pragma unroll
      for (int cf = 0; cf < 8; cf++)
        acc[rf][cf] = __builtin_amdgcn_mfma_f32_16x16x32_bf16(
            af[rf], bf[cf], acc[rf][cf], 0, 0, 0);
  }

  // acc C/D: o = cf*16 + lr, i = i0 + rf*16 + lg*4 + reg.
  // Consumer layout: lane L of (t,cf) holds E[i = t*32 + (L>>4)*8 + j][o =
  // cf*16 + (L&15)], j=0..7. Our 4 regs are half of one 8-run:
  //   t = (i0 + rf*16) >> 5, L = ((2*rf + (lg>>1)) & 3)*16 + lr, j0 = (lg&1)*4
  unsigned short* Bm = Bpack + (size_t)m * BPACK_M;
#pragma unroll
  for (int rf = 0; rf < 2; rf++) {
    const int t = (i0 + rf * 16) >> 5;
    const int L = ((2 * rf + (lg >> 1)) & 3) * 16 + lr;
#pragma unroll
    for (int cf = 0; cf < 8; cf++) {
      ushort4 pk;
      pk.x = f2bf(acc[rf][cf][0]);
      pk.y = f2bf(acc[rf][cf][1]);
      pk.z = f2bf(acc[rf][cf][2]);
      pk.w = f2bf(acc[rf][cf][3]);
      *(ushort4*)(Bm + (size_t)(t * 8 + cf) * 512 + L * 8 + (lg & 1) * 4) = pk;
    }
  }
}

// ---------------- Kernel 2: main GEMM, m-quad blocks ----------------
// grid: (NM/4, NBATCH/32). 256 threads = 4 waves; wave w owns m = 4*bx + w,
// b-rows b0..b0+31 (b0 = by*32), all 128 o. Block reads psiHat 4KB-contiguous
// per b-row; writes out 2KB-contiguous per b-row.
#define LOADB(BUF, t)                                                   \
  _Pragma("unroll")                                                     \
  for (int cf = 0; cf < 8; cf++)                                        \
    BUF[cf] = *(const short8*)(Bm + ((t) * 8 + cf) * 512 + lane * 8);

#define SB __builtin_amdgcn_sched_barrier(0)

#define MFMA8(A0, A1, BUF)                                              \
  _Pragma("unroll")                                                     \
  for (int cf = 0; cf < 8; cf++) {                                      \
    acc[0][cf] = __builtin_amdgcn_mfma_f32_16x16x32_bf16(               \
        A0, BUF[cf], acc[0][cf], 0, 0, 0);                              \
    acc[1][cf] = __builtin_amdgcn_mfma_f32_16x16x32_bf16(               \
        A1, BUF[cf], acc[1][cf], 0, 0, 0);                              \
  }

__global__ __launch_bounds__(256, 2) void fdlt_main(
    const float* __restrict__ psiHat,
    const unsigned short* __restrict__ Bpack,
    float* __restrict__ out)
{
  const int tid = threadIdx.x;
  const int lane = tid & 63;
  const int w = tid >> 6;
  const int m = blockIdx.x * 4 + w;      // wave-private m; block = 4 adjacent m
  const int b0 = blockIdx.y * 32;
  const int lr = lane & 15;
  const int lg = lane >> 4;

  f32x4 acc[2][8];
#pragma unroll
  for (int a = 0; a < 2; a++)
#pragma unroll
    for (int b = 0; b < 8; b++) acc[a][b] = (f32x4)0.f;

  const unsigned short* __restrict__ Bm = Bpack + (size_t)m * BPACK_M;
  const float* arow0 = psiHat + ((size_t)(b0 + lr) * NM + m) * NI + lg * 8;
  const float* arow1 = arow0 + (size_t)16 * NM * NI;

  // ---- issue A half-0 (16 independent dwordx4), pinned ----
  float4 xa0[16];
#pragma unroll
  for (int tt = 0; tt < 4; tt++) {
    xa0[tt * 2]         = *(const float4*)(arow0 + tt * 32);
    xa0[tt * 2 + 1]     = *(const float4*)(arow0 + tt * 32 + 4);
    xa0[8 + tt * 2]     = *(const float4*)(arow1 + tt * 32);
    xa0[8 + tt * 2 + 1] = *(const float4*)(arow1 + tt * 32 + 4);
  }
  SB;

  // ---- cvt half-0 (waits xa0; frees it) ----
  short8 af0[2][4];
#pragma unroll
  for (int tt = 0; tt < 4; tt++) {
    af0[0][tt] = cvt8(xa0[tt * 2], xa0[tt * 2 + 1], 1.0f);
    af0[1][tt] = cvt8(xa0[8 + tt * 2], xa0[8 + tt * 2 + 1], 1.0f);
  }

  // ---- issue B[0], then A half-1; all in flight across half-0 compute ----
  short8 bf0[8], bf1[8];
  LOADB(bf0, 0);
  float4 xa1[16];
#pragma unroll
  for (int tt = 0; tt < 4; tt++) {
    xa1[tt * 2]         = *(const float4*)(arow0 + (4 + tt) * 32);
    xa1[tt * 2 + 1]     = *(const float4*)(arow0 + (4 + tt) * 32 + 4);
    xa1[8 + tt * 2]     = *(const float4*)(arow1 + (4 + tt) * 32);
    xa1[8 + tt * 2 + 1] = *(const float4*)(arow1 + (4 + tt) * 32 + 4);
  }
  SB;

  // ---- 8 k-steps, B ping-pong, B[t+1] issued before MFMA(t) ----
  LOADB(bf1, 1); SB; MFMA8(af0[0][0], af0[1][0], bf0);
  LOADB(bf0, 2); SB; MFMA8(af0[0][1], af0[1][1], bf1);
  LOADB(bf1, 3); SB; MFMA8(af0[0][2], af0[1][2], bf0);
  LOADB(bf0, 4); SB; MFMA8(af0[0][3], af0[1][3], bf1);

  // cvt half-1 (xa1 has had ~4 k-steps to arrive; frees xa1)
  short8 af1[2][4];
#pragma unroll
  for (int tt = 0; tt < 4; tt++) {
    af1[0][tt] = cvt8(xa1[tt * 2], xa1[tt * 2 + 1], 1.0f);
    af1[1][tt] = cvt8(xa1[8 + tt * 2], xa1[8 + tt * 2 + 1], 1.0f);
  }

  LOADB(bf1, 5); SB; MFMA8(af1[0][0], af1[1][0], bf0);
  LOADB(bf0, 6); SB; MFMA8(af1[0][1], af1[1][1], bf1);
  LOADB(bf1, 7); SB; MFMA8(af1[0][2], af1[1][2], bf0);
                 SB; MFMA8(af1[0][3], af1[1][3], bf1);

  // out[b][m][o]; C/D: col = lane&15 (= o), row = (lane>>4)*4+reg (= b offset)
#pragma unroll
  for (int rf = 0; rf < 2; rf++)
#pragma unroll
    for (int cf = 0; cf < 8; cf++) {
      const int o = cf * 16 + lr;
#pragma unroll
      for (int r = 0; r < 4; r++) {
        const int b = b0 + rf * 16 + lg * 4 + r;
        out[((size_t)b * NM + m) * NO + o] = acc[rf][cf][r];
      }
    }
}

extern "C" void kernel_launch(void* const* d_in, const int* in_sizes, int n_in,
                              void* d_out, int out_size, void* d_ws, size_t ws_size,
                              hipStream_t stream) {
  const float* psiHat = (const float*)d_in[0];
  const float* cm     = (const float*)d_in[1];
  const float* XFc    = (const float*)d_in[2];
  const float* XFs    = (const float*)d_in[3];
  const float* D      = (const float*)d_in[4];
  float* out = (float*)d_out;
  unsigned short* Bpack = (unsigned short*)d_ws;  // 128*32768*2 = 8.39 MB

  e_kernel<<<256, 256, 0, stream>>>(XFc, XFs, D, cm, Bpack);
  fdlt_main<<<dim3(NM / 4, NBATCH / 32), 256, 0, stream>>>(psiHat, Bpack, out);
}

// Round 8
// 117.352 us; speedup vs baseline: 1.0761x; 1.0761x over previous
//
#include <hip/hip_runtime.h>

// FDLT: out[b,m,o] = sum_i psiHat[b,m,i] * E[m][i][o]
//   E[m] = cm * X_parity(m) @ D[m]^T   (X = XFc even m, XFs odd m)
// BATCH=2048, B=128 (m), N=256 (i), O=128 (o)
//
// Kernel 1: e_kernel -> Bpack[m][t][cf][lane]·16B (MFMA fragment-packed ->
//   main-kernel B-loads are wave-uniform base + lane*16: dense 1KB bursts).
// Kernel 2: A staged via global_load_lds where EACH instruction reads one
//   full 1KB contiguous psiHat row (memcpy-shaped DRAM bursts — the one
//   pattern proven to sustain 6+ TB/s). Block = 64 b x 1 m x full K=256,
//   64KB LDS single-buffered, 2 blocks/CU overlap. 32B-unit XOR swizzle
//   (unit ^= row&7) applied to glds SOURCE and ds_read both (rule #21).

typedef __attribute__((ext_vector_type(8))) short short8;
typedef __attribute__((ext_vector_type(4))) float f32x4;

#define NBATCH 2048
#define NM 128
#define NI 256   // K dim (i / j)
#define NO 128   // output o dim
// Bpack per m: 8 t-steps x 8 cf x 64 lanes x 8 bf16 = 32768 shorts (64 KB)
#define BPACK_M 32768

#define GLB(p) ((const __attribute__((address_space(1))) void*)(p))
#define LDS(p) ((__attribute__((address_space(3))) void*)(p))

__device__ __forceinline__ unsigned short f2bf(float f) {
  // round-to-nearest-even fp32 -> bf16
  unsigned int u = __builtin_bit_cast(unsigned int, f);
  u += 0x7FFFu + ((u >> 16) & 1u);
  return (unsigned short)(u >> 16);
}

__device__ __forceinline__ short8 cvt8(float4 a, float4 b, float s) {
  short8 v;
  v[0] = (short)f2bf(s * a.x); v[1] = (short)f2bf(s * a.y);
  v[2] = (short)f2bf(s * a.z); v[3] = (short)f2bf(s * a.w);
  v[4] = (short)f2bf(s * b.x); v[5] = (short)f2bf(s * b.y);
  v[6] = (short)f2bf(s * b.z); v[7] = (short)f2bf(s * b.w);
  return v;
}

// ---------------- Kernel 1: E precompute -> fragment-packed Bpack ----------
__global__ __launch_bounds__(256) void e_kernel(
    const float* __restrict__ XFc, const float* __restrict__ XFs,
    const float* __restrict__ D, const float* __restrict__ cmp,
    unsigned short* __restrict__ Bpack)
{
  const int m = blockIdx.x >> 1;
  const int ihalf = blockIdx.x & 1;
  const int tid = threadIdx.x;
  const int lane = tid & 63;
  const int w = tid >> 6;
  const int lr = lane & 15;   // frag row (A) / col (B)
  const int lg = lane >> 4;   // k group
  const float cm = cmp[0];
  const float* __restrict__ Xp = (m & 1) ? XFs : XFc;
  const float* __restrict__ Dm = D + (size_t)m * (NO * NI);
  const int i0 = ihalf * 128 + w * 32;   // multiple of 32

  f32x4 acc[2][8];
#pragma unroll
  for (int a = 0; a < 2; a++)
#pragma unroll
    for (int b = 0; b < 8; b++) acc[a][b] = (f32x4)0.f;

  for (int kk = 0; kk < NI; kk += 32) {
    const int kb = kk + lg * 8;
    short8 af[2];
#pragma unroll
    for (int rf = 0; rf < 2; rf++) {
      const float* ap = Xp + (size_t)(i0 + rf * 16 + lr) * NI + kb;
      float4 x0 = *(const float4*)ap;
      float4 x1 = *(const float4*)(ap + 4);
      af[rf] = cvt8(x0, x1, cm);
    }
    short8 bf[8];
#pragma unroll
    for (int cf = 0; cf < 8; cf++) {
      const float* bp = Dm + (size_t)(cf * 16 + lr) * NI + kb;
      float4 x0 = *(const float4*)bp;
      float4 x1 = *(const float4*)(bp + 4);
      bf[cf] = cvt8(x0, x1, 1.0f);
    }
#pragma unroll
    for (int rf = 0; rf < 2; rf++)
#pragma unroll
      for (int cf = 0; cf < 8; cf++)
        acc[rf][cf] = __builtin_amdgcn_mfma_f32_16x16x32_bf16(
            af[rf], bf[cf], acc[rf][cf], 0, 0, 0);
  }

  // acc C/D: o = cf*16 + lr, i = i0 + rf*16 + lg*4 + reg.
  // Consumer layout: lane L of (t,cf) holds E[i = t*32 + (L>>4)*8 + j][o =
  // cf*16 + (L&15)], j=0..7. Our 4 regs are half of one 8-run:
  //   t = (i0 + rf*16) >> 5, L = ((2*rf + (lg>>1)) & 3)*16 + lr, j0 = (lg&1)*4
  unsigned short* Bm = Bpack + (size_t)m * BPACK_M;
#pragma unroll
  for (int rf = 0; rf < 2; rf++) {
    const int t = (i0 + rf * 16) >> 5;
    const int L = ((2 * rf + (lg >> 1)) & 3) * 16 + lr;
#pragma unroll
    for (int cf = 0; cf < 8; cf++) {
      ushort4 pk;
      pk.x = f2bf(acc[rf][cf][0]);
      pk.y = f2bf(acc[rf][cf][1]);
      pk.z = f2bf(acc[rf][cf][2]);
      pk.w = f2bf(acc[rf][cf][3]);
      *(ushort4*)(Bm + (size_t)(t * 8 + cf) * 512 + L * 8 + (lg & 1) * 4) = pk;
    }
  }
}

// ---------------- Kernel 2: main GEMM, row-burst glds staging --------------
// grid: (NM fast, NBATCH/64). 256 threads = 4 waves; block = 64(b) x 128(o)
// at one m; wave w computes rows r0 = w*16 .. +15, all 128 o, full K=256.
// LDS As: [64 rows][1024B]. Physical 32B-unit p of row r holds logical
// 32B-unit (p ^ (r&7)) of psiHat row — realized by pre-swizzling the glds
// SOURCE (LDS dest stays linear), undone by the same XOR on ds_read.
#define LOADB(BUF, t)                                                   \
  _Pragma("unroll")                                                     \
  for (int cf = 0; cf < 8; cf++)                                        \
    BUF[cf] = *(const short8*)(Bm + ((t) * 8 + cf) * 512 + lane * 8);

#define SB __builtin_amdgcn_sched_barrier(0)

__global__ __launch_bounds__(256, 2) void fdlt_main(
    const float* __restrict__ psiHat,
    const unsigned short* __restrict__ Bpack,
    float* __restrict__ out)
{
  __shared__ float As_f[64 * 256];   // 64 KB
  const int m = blockIdx.x;
  const int tid = threadIdx.x;
  const int lane = tid & 63;
  const int w = tid >> 6;
  const int b0 = blockIdx.y * 64;
  const int lr = lane & 15;
  const int lg = lane >> 4;
  char* As = (char*)As_f;

  // ---- stage: 16 glds per wave, each = one full 1KB contiguous row ----
  // lane covers 16B-unit u of the row; logical 32B-unit = u>>1, piece = u&1;
  // source float offset = (((u>>1) ^ (r&7)) << 3) + ((u&1) << 2).
#pragma unroll
  for (int s = 0; s < 16; s++) {
    const int r = s * 4 + w;
    const int fofs = ((((lane >> 1) ^ (r & 7)) << 3) + ((lane & 1) << 2));
    const float* src = psiHat + ((size_t)(b0 + r) * NM + m) * NI + fofs;
    __builtin_amdgcn_global_load_lds(GLB(src), LDS(As + r * 1024), 16, 0, 0);
  }

  f32x4 acc[8];
#pragma unroll
  for (int b = 0; b < 8; b++) acc[b] = (f32x4)0.f;

  const unsigned short* __restrict__ Bm = Bpack + (size_t)m * BPACK_M;

  // B[0] prefetch overlaps the stage drain (independent of LDS)
  short8 bf0[8], bf1[8];
  LOADB(bf0, 0);
  SB;

  __syncthreads();   // vmcnt(0) drain + barrier: As ready

  const int arow = w * 16 + lr;          // this lane's A row
  const char* Arow = As + arow * 1024;
  const int rsw = lr & 7;                // == arow & 7 (w*16 % 8 == 0)

#pragma unroll
  for (int t = 0; t < 8; t++) {
    // prefetch next B while computing this step
    if (t < 7) { LOADB(((t & 1) ? bf0 : bf1), t + 1); SB; }
    // A-frag from LDS: logical 32B-unit L = t*4 + lg, phys = L ^ rsw
    const int p = ((t * 4 + lg) ^ rsw) << 5;
    float4 x0 = *(const float4*)(Arow + p);
    float4 x1 = *(const float4*)(Arow + p + 16);
    short8 af = cvt8(x0, x1, 1.0f);
    const short8* bf = (t & 1) ? bf1 : bf0;
#pragma unroll
    for (int cf = 0; cf < 8; cf++)
      acc[cf] = __builtin_amdgcn_mfma_f32_16x16x32_bf16(
          af, bf[cf], acc[cf], 0, 0, 0);
  }

  // out[b][m][o]; C/D: col = lane&15 (= o), row = (lane>>4)*4+reg (= b offset)
#pragma unroll
  for (int cf = 0; cf < 8; cf++) {
    const int o = cf * 16 + lr;
#pragma unroll
    for (int r = 0; r < 4; r++) {
      const int b = b0 + w * 16 + lg * 4 + r;
      out[((size_t)b * NM + m) * NO + o] = acc[cf][r];
    }
  }
}

extern "C" void kernel_launch(void* const* d_in, const int* in_sizes, int n_in,
                              void* d_out, int out_size, void* d_ws, size_t ws_size,
                              hipStream_t stream) {
  const float* psiHat = (const float*)d_in[0];
  const float* cm     = (const float*)d_in[1];
  const float* XFc    = (const float*)d_in[2];
  const float* XFs    = (const float*)d_in[3];
  const float* D      = (const float*)d_in[4];
  float* out = (float*)d_out;
  unsigned short* Bpack = (unsigned short*)d_ws;  // 128*32768*2 = 8.39 MB

  e_kernel<<<256, 256, 0, stream>>>(XFc, XFs, D, cm, Bpack);
  fdlt_main<<<dim3(NM, NBATCH / 64), 256, 0, stream>>>(psiHat, Bpack, out);
}